// Round 5
// baseline (122.545 us; speedup 1.0000x reference)
//
#include <hip/hip_runtime.h>

#define PI_F 3.141592653f
#define NB 1024
#define NW 16            // 16 x u64 words per 1024-bit row
#define IOU_THR_F 0.1f

__device__ __forceinline__ float limit_period_f(float v) {
    return v - floorf(v / (2.0f * PI_F) + 0.5f) * (2.0f * PI_F);
}

// swizzled word index: word w of row r lives at r*16 + (w ^ (r&15))
__device__ __forceinline__ int widx(int r, int w) {
    return (r << 4) | (w ^ (r & 15));
}

// ---------------------------------------------------------------------------
// K1a: conservative prefilter -> candidate mask (superset of true mask) into
// maskT/flagT, plus compact candidate list (diagonal excluded: iou(a,a)=1).
// Block = j (matT row); lanes iterate i (4 per thread). Divergence-free.
// d > rA+rB => rects disjoint => iou=0; (ra+rb)^2 <= 2(ra2+rb2) (AM-GM).
// ---------------------------------------------------------------------------
__global__ __launch_bounds__(256) void prefilter_kernel(
    const float* __restrict__ boxes,
    unsigned long long* __restrict__ maskT,
    unsigned char* __restrict__ flagT,
    unsigned int* __restrict__ counter,
    unsigned int* __restrict__ candlist)
{
    const int tid = threadIdx.x;
    const int lane = tid & 63;
    const int j = blockIdx.x;

    const float xj  = boxes[j*7+0], yj  = boxes[j*7+1];
    const float dxj = boxes[j*7+3], dyj = boxes[j*7+4];
    const float rb2 = 0.25f*(dxj*dxj + dyj*dyj);

    #pragma unroll
    for (int q = 0; q < 4; ++q) {
        const int i = q*256 + tid;
        const float xi  = boxes[i*7+0], yi  = boxes[i*7+1];
        const float dxi = boxes[i*7+3], dyi = boxes[i*7+4];
        const float ddx = xi - xj, ddy = yi - yj;
        const float d2 = ddx*ddx + ddy*ddy;
        const float ra2 = 0.25f*(dxi*dxi + dyi*dyi);
        const bool cand = d2 <= 2.0f*(ra2 + rb2);

        const unsigned long long bal = __ballot(cand);
        const int w = q*4 + (tid >> 6);          // == i>>6
        if (lane == 0) {
            maskT[(size_t)j*NW + w] = bal;       // superset; K1b clears failures
            flagT[j*NW + w] = (bal != 0ull) ? 1 : 0;
        }

        // append candidates, excluding the diagonal bit (always passes)
        unsigned long long keep = bal;
        if ((j >> 6) == w) keep &= ~(1ull << (j & 63));
        unsigned int base = 0;
        if (lane == 0 && keep) base = atomicAdd(counter, (unsigned)__popcll(keep));
        base = __shfl(base, 0);
        if ((keep >> lane) & 1ull) {
            const unsigned int pos = base + (unsigned)__popcll(keep & ((1ull << lane) - 1ull));
            candlist[pos] = ((unsigned)j << 10) | (unsigned)i;
        }
    }
}

// ---------------------------------------------------------------------------
// K1b: exact rotated-BEV IoU for the compact candidate list; clears the bit
// when iou <= thr. One thread per candidate -> no wasted wave-wide clips.
// Math is bit-identical to the reference path: A=boxes[i] polygon clipped by
// B=boxes[j] edges (matT[j] bit i == ious[i][j] > 0.1).
// ---------------------------------------------------------------------------
__global__ __launch_bounds__(256) void iou_exact_kernel(
    const float* __restrict__ boxes,
    const unsigned int* __restrict__ counter,
    const unsigned int* __restrict__ candlist,
    unsigned long long* __restrict__ maskT)
{
    __shared__ float vxs[2][8][256];
    __shared__ float vys[2][8][256];
    const int tid = threadIdx.x;
    const unsigned int total = counter[0];

    for (unsigned int idx = blockIdx.x*256 + tid; idx < total; idx += gridDim.x*256) {
        const unsigned int e = candlist[idx];
        const int j = (int)(e >> 10);
        const int i = (int)(e & 1023u);

        const float xi  = boxes[i*7+0], yi  = boxes[i*7+1], zi  = boxes[i*7+2];
        const float dxi = boxes[i*7+3], dyi = boxes[i*7+4], dzi = boxes[i*7+5];
        const float aang = limit_period_f(boxes[i*7+6]);
        const float xj  = boxes[j*7+0], yj  = boxes[j*7+1], zj  = boxes[j*7+2];
        const float dxj = boxes[j*7+3], dyj = boxes[j*7+4], dzj = boxes[j*7+5];
        const float bang = limit_period_f(boxes[j*7+6]);

        float ca, sa, cb, sb;
        sincosf(aang, &sa, &ca);
        sincosf(bang, &sb, &cb);

        // A corners -> LDS buf 0 (per-lane column tid)
        {
            const float hx = 0.5f*dxi, hy = 0.5f*dyi;
            const float lxs[4] = { hx, -hx, -hx, hx };
            const float lys[4] = { hy, hy, -hy, -hy };
            #pragma unroll
            for (int k = 0; k < 4; ++k) {
                vxs[0][k][tid] = lxs[k]*ca - lys[k]*sa + xi;
                vys[0][k][tid] = lxs[k]*sa + lys[k]*ca + yi;
            }
        }
        // B corners (clip edges)
        float pbx[4], pby[4];
        {
            const float hx = 0.5f*dxj, hy = 0.5f*dyj;
            const float lxs[4] = { hx, -hx, -hx, hx };
            const float lys[4] = { hy, hy, -hy, -hy };
            #pragma unroll
            for (int k = 0; k < 4; ++k) {
                pbx[k] = lxs[k]*cb - lys[k]*sb + xj;
                pby[k] = lxs[k]*sb + lys[k]*cb + yj;
            }
        }

        int n = 4;
        int cur = 0;
        #pragma unroll
        for (int e4 = 0; e4 < 4; ++e4) {
            const float eax = pbx[e4], eay = pby[e4];
            const float ebx2 = pbx[(e4+1)&3], eby2 = pby[(e4+1)&3];
            const float dx = ebx2 - eax, dy = eby2 - eay;
            int m = 0;
            if (n > 0) {
                int pidx = n - 1; if (pidx > 7) pidx = 7;
                float px = vxs[cur][pidx][tid];
                float py = vys[cur][pidx][tid];
                float sq = dx*(py - eay) - dy*(px - eax);
                #pragma unroll
                for (int k = 0; k < 8; ++k) {
                    if (k < n) {
                        const float cx = vxs[cur][k][tid];
                        const float cy = vys[cur][k][tid];
                        const float sp = dx*(cy - eay) - dy*(cx - eax);
                        const bool in_p = (sp >= 0.0f);
                        const bool in_q = (sq >= 0.0f);
                        if (in_p != in_q) {
                            float den = sq - sp;
                            den = (fabsf(den) < 1e-9f) ? 1e-9f : den;   // ref semantics
                            const float t = sq / den;
                            if (m < 8) {
                                vxs[cur^1][m][tid] = px + t*(cx - px);
                                vys[cur^1][m][tid] = py + t*(cy - py);
                            }
                            ++m;
                        }
                        if (in_p) {
                            if (m < 8) {
                                vxs[cur^1][m][tid] = cx;
                                vys[cur^1][m][tid] = cy;
                            }
                            ++m;
                        }
                        px = cx; py = cy; sq = sp;
                    }
                }
            }
            n = m;
            cur ^= 1;
        }

        float area = 0.0f;
        if (n >= 3) {
            float s = 0.0f;
            const float x0 = vxs[cur][0][tid];
            const float y0 = vys[cur][0][tid];
            #pragma unroll
            for (int k = 0; k < 8; ++k) {
                if (k < n) {
                    float nx, ny;
                    if (k == n - 1) { nx = x0; ny = y0; }
                    else {
                        int nk = k + 1; if (nk > 7) nk = 7;
                        nx = vxs[cur][nk][tid]; ny = vys[cur][nk][tid];
                    }
                    s += vxs[cur][k][tid]*ny - vys[cur][k][tid]*nx;
                }
            }
            area = 0.5f * fabsf(s);
        }

        const float zh = fminf(zi + dzi*0.5f, zj + dzj*0.5f);
        const float zl = fmaxf(zi - dzi*0.5f, zj - dzj*0.5f);
        const float h = fmaxf(zh - zl, 0.0f);
        const float inter = area * h;
        const float va = dxi*dyi*dzi;
        const float vb = dxj*dyj*dzj;
        const float iou = inter / fmaxf(va + vb - inter, 1e-6f);

        if (!(iou > IOU_THR_F)) {
            atomicAnd(&maskT[(size_t)j*NW + (i >> 6)], ~(1ull << (i & 63)));
        }
    }
}

// ---------------------------------------------------------------------------
// K2: clustering via transposed matrix. 1 block x 256 threads.
// (flag=1 words that became zero after K1b's clears read as 0 -> harmless.)
// ---------------------------------------------------------------------------
__global__ __launch_bounds__(256) void cluster_kernel(
    const unsigned long long* __restrict__ maskT,
    const unsigned char* __restrict__ flagT,
    int* __restrict__ ci_out)
{
    extern __shared__ char smem[];
    unsigned long long* mat = (unsigned long long*)smem;                 // 128 KB (sparse-filled)
    unsigned short* wm = (unsigned short*)(smem + 131072);               // 1024 u16
    unsigned long long* seed_lds = (unsigned long long*)(smem + 133120); // 16 u64
    int* rankb = (int*)(smem + 133248);                                  // 16 int

    const int tid = threadIdx.x;

    // ---- phase A: sparse staging of matT ----
    if (tid < NW) { seed_lds[tid] = 0ull; rankb[tid] = 0; }
    #pragma unroll
    for (int rr = 0; rr < 4; ++rr) {
        const int r = tid + rr * 256;
        const uint4 f = *(const uint4*)(flagT + r * NW);
        unsigned int m16 = 0;
        #define NIBX(v, sh) \
            { if ((v) & 0x000000FFu) m16 |= 1u << (sh); \
              if ((v) & 0x0000FF00u) m16 |= 1u << ((sh)+1); \
              if ((v) & 0x00FF0000u) m16 |= 1u << ((sh)+2); \
              if ((v) & 0xFF000000u) m16 |= 1u << ((sh)+3); }
        NIBX(f.x, 0) NIBX(f.y, 4) NIBX(f.z, 8) NIBX(f.w, 12)
        #undef NIBX
        wm[r] = (unsigned short)m16;
        unsigned int t16 = m16;
        while (t16) {
            const int w = __ffs(t16) - 1;
            t16 &= t16 - 1;
            mat[widx(r, w)] = maskT[r * NW + w];
        }
    }
    __syncthreads();

    // ---- phase B: wave 0, 16 sequential chunks ----
    if (tid < 64) {
        int base = 0;
        for (int c = 0; c < NW; ++c) {
            const int row = c * 64 + tid;
            unsigned int f = (unsigned int)wm[row];
            unsigned long long acc = 0ull, Dt = 0ull;
            while (f) {
                const int w = __ffs(f) - 1;
                f &= f - 1;
                const unsigned long long v = mat[widx(row, w)];
                acc |= v & seed_lds[w];          // seeds of future chunks are 0
                if (w == c) Dt = v;              // in-edges within my chunk
            }
            const bool elig = (acc == 0ull);
            const unsigned long long E = __ballot(elig);
            const unsigned long long inlow = Dt & ((1ull << tid) - 1ull);

            // ballot fixpoint: S(j) = E(j) && no seed t<j with edge t->j
            unsigned long long S = E;
            #pragma unroll 1
            for (int it = 0; it < 64; ++it) {
                const bool killed = (inlow & S) != 0ull;
                const unsigned long long S2 = E & __ballot(!killed);
                if (S2 == S) break;
                S = S2;
            }

            if (tid == 0) { seed_lds[c] = S; rankb[c] = base; }
            base += (int)__popcll(S);
        }
    }
    __syncthreads();

    // ---- phase C: label(j) = rank of max-index seed covering j ----
    #pragma unroll
    for (int rr = 0; rr < 4; ++rr) {
        const int r = tid + rr * 256;
        unsigned int f = (unsigned int)wm[r];
        int best = -1;
        while (f) {
            const int w = __ffs(f) - 1;
            f &= f - 1;
            const unsigned long long bits = mat[widx(r, w)] & seed_lds[w];
            if (bits) best = (w << 6) | (63 - __clzll(bits));  // w ascending -> monotone
        }
        int lbl = 0;
        if (best >= 0) {
            const int w = best >> 6, pos = best & 63;
            lbl = rankb[w] + (int)__popcll(seed_lds[w] & ((1ull << pos) - 1ull)) + 1;
        }
        ci_out[r] = lbl;
    }
}

// ---------------------------------------------------------------------------
// K3: per-cluster fusion. 1024 blocks x 64 threads (1 wave).
// ---------------------------------------------------------------------------
__global__ __launch_bounds__(64) void fuse_kernel(
    const float* __restrict__ boxes,
    const float* __restrict__ scores,
    const int* __restrict__ ci,
    float* __restrict__ out)
{
    __shared__ float ms[NB];
    __shared__ int   mi[NB];

    const int b = blockIdx.x;
    const int lane = threadIdx.x;
    const int target = b + 1;

    unsigned int mymask = 0;
    const int4* ci4 = (const int4*)ci;
    #pragma unroll
    for (int k4 = 0; k4 < 4; ++k4) {
        const int4 v = ci4[lane * 4 + k4];
        if (v.x == target) mymask |= 1u << (k4*4+0);
        if (v.y == target) mymask |= 1u << (k4*4+1);
        if (v.z == target) mymask |= 1u << (k4*4+2);
        if (v.w == target) mymask |= 1u << (k4*4+3);
    }
    const bool anyv = (__ballot(mymask != 0) != 0ULL);

    float* outb = out + (size_t)b * 7;
    float* outs = out + 7 * NB;
    float* outv = out + 8 * NB;

    if (!anyv) {
        if (lane == 0) {
            #pragma unroll
            for (int c = 0; c < 7; ++c) outb[c] = 0.0f;
            outs[b] = 0.0f;
            outv[b] = 0.0f;
        }
        return;
    }

    // pass 1: ssum + argmax (first index of max)
    float ssum = 0.0f, smax = -1.0f;
    int sidx = 1 << 30;
    #pragma unroll
    for (int k = 0; k < 16; ++k) {
        if (mymask & (1u << k)) {
            const int idx = lane * 16 + k;
            const float s = scores[idx];
            ssum += s;
            if (s > smax || (s == smax && idx < sidx)) { smax = s; sidx = idx; }
        }
    }
    #pragma unroll
    for (int off = 32; off >= 1; off >>= 1) {
        ssum += __shfl_xor(ssum, off);
        const float om = __shfl_xor(smax, off);
        const int   oi = __shfl_xor(sidx, off);
        if (om > smax || (om == smax && oi < sidx)) { smax = om; sidx = oi; }
    }
    const float ref = limit_period_f(boxes[sidx * 7 + 6]);

    // pass 2: sc_gt
    float sc_gt = 0.0f;
    #pragma unroll
    for (int k = 0; k < 16; ++k) {
        if (mymask & (1u << k)) {
            const int idx = lane * 16 + k;
            const float dir = limit_period_f(boxes[idx * 7 + 6]);
            float diff = fabsf(dir - ref);
            if (diff > PI_F) diff = 2.0f * PI_F - diff;
            if (diff > PI_F * 0.5f) sc_gt += scores[idx];
        }
    }
    #pragma unroll
    for (int off = 32; off >= 1; off >>= 1) sc_gt += __shfl_xor(sc_gt, off);
    const bool flip_gt = (sc_gt <= (ssum - sc_gt));

    // pass 3: weighted sums (6 center comps + sin + cos)
    float acc[6] = {0,0,0,0,0,0};
    float ssin = 0.0f, scos = 0.0f;
    #pragma unroll
    for (int k = 0; k < 16; ++k) {
        if (mymask & (1u << k)) {
            const int idx = lane * 16 + k;
            const float s = scores[idx];
            const float w = s / ssum;
            const float dir = limit_period_f(boxes[idx * 7 + 6]);
            float diff = fabsf(dir - ref);
            if (diff > PI_F) diff = 2.0f * PI_F - diff;
            const bool gt = (diff > PI_F * 0.5f);
            const bool add = flip_gt ? gt : (!gt);
            const float d2 = limit_period_f(dir + (add ? PI_F : 0.0f));
            float sd, cd;
            sincosf(d2, &sd, &cd);
            ssin += sd * w;
            scos += cd * w;
            #pragma unroll
            for (int c = 0; c < 6; ++c) acc[c] += boxes[idx * 7 + c] * w;
        }
    }
    #pragma unroll
    for (int off = 32; off >= 1; off >>= 1) {
        ssin += __shfl_xor(ssin, off);
        scos += __shfl_xor(scos, off);
        #pragma unroll
        for (int c = 0; c < 6; ++c) acc[c] += __shfl_xor(acc[c], off);
    }
    const float theta = atan2f(ssin, scos);

    // pass 4: score fusion via tie-broken ranks (matches sorted-power sum)
    const int cnt = __popc(mymask);
    int x = cnt;
    #pragma unroll
    for (int off = 1; off < 64; off <<= 1) {
        const int y = __shfl_up(x, off);
        if (lane >= off) x += y;
    }
    const int base = x - cnt;
    const int K = __shfl(x, 63);
    {
        int p = base;
        #pragma unroll
        for (int k = 0; k < 16; ++k) {
            if (mymask & (1u << k)) {
                const int idx = lane * 16 + k;
                ms[p] = scores[idx];
                mi[p] = idx;
                ++p;
            }
        }
    }
    __syncthreads();

    float sf = 0.0f;
    for (int e = lane; e < K; e += 64) {
        const float v = ms[e];
        const int ix = mi[e];
        int rank = 0;
        for (int t = 0; t < K; ++t) {
            const float u = ms[t];
            if (u > v || (u == v && mi[t] < ix)) ++rank;
        }
        sf += powf(v, (float)(rank + 1));
    }
    #pragma unroll
    for (int off = 32; off >= 1; off >>= 1) sf += __shfl_xor(sf, off);
    sf = fminf(sf, 1.0f);

    if (lane == 0) {
        #pragma unroll
        for (int c = 0; c < 6; ++c) outb[c] = acc[c];
        outb[6] = theta;
        outs[b] = sf;
        outv[b] = 1.0f;
    }
}

// ---------------------------------------------------------------------------
extern "C" void kernel_launch(void* const* d_in, const int* in_sizes, int n_in,
                              void* d_out, int out_size, void* d_ws, size_t ws_size,
                              hipStream_t stream) {
    const float* boxes  = (const float*)d_in[0];   // (1024,7) f32
    const float* scores = (const float*)d_in[1];   // (1024,)  f32
    float* out = (float*)d_out;

    // ws layout
    unsigned long long* maskT = (unsigned long long*)d_ws;               // 128 KB @ 0
    int* ci = (int*)((char*)d_ws + 131072);                              // 4 KB
    unsigned char* flagT = (unsigned char*)d_ws + 135168;                // 16 KB -> 151552
    unsigned int* counter = (unsigned int*)((char*)d_ws + 151552);       // 4 B (pad to 151616)
    unsigned int* candlist = (unsigned int*)((char*)d_ws + 151616);      // cap 1M entries = 4 MB

    hipMemsetAsync(counter, 0, sizeof(unsigned int), stream);

    prefilter_kernel<<<NB, 256, 0, stream>>>(boxes, maskT, flagT, counter, candlist);
    iou_exact_kernel<<<64, 256, 0, stream>>>(boxes, counter, candlist, maskT);

    const size_t SMEM = 133312;  // 128K mat + 2K wm + seeds + rankbase
    (void)hipFuncSetAttribute((const void*)cluster_kernel,
                              hipFuncAttributeMaxDynamicSharedMemorySize, (int)SMEM);
    cluster_kernel<<<1, 256, SMEM, stream>>>(maskT, flagT, ci);

    fuse_kernel<<<NB, 64, 0, stream>>>(boxes, scores, ci, out);
}